// Round 12
// baseline (60.247 us; speedup 1.0000x reference)
//
#include <hip/hip_runtime.h>
#include <stdint.h>

constexpr int Bn = 8, Cn = 64, Hn = 128, Wn = 128;
constexpr int HsC = 64, WsC = 64;
constexpr int Kn = 256;                 // C * r^2
constexpr int PX = HsC * WsC;           // 4096 pixels per (t,b) plane
constexpr float DECAYF = 0.25f;

typedef __attribute__((ext_vector_type(8))) short short8v;
typedef __attribute__((ext_vector_type(4))) float f32x4;

#define WAITV(N) asm volatile("s_waitcnt vmcnt(" #N ")" ::: "memory")
#define WAITL0() asm volatile("s_waitcnt lgkmcnt(0)" ::: "memory")
#define BAR() __builtin_amdgcn_s_barrier()

static __device__ __forceinline__ ushort f2bf_rn(float f) {
    uint32_t u = __float_as_uint(f);
    uint32_t r = (u + 0x7FFFu + ((u >> 16) & 1u)) >> 16;
    return (ushort)r;
}
static __device__ __forceinline__ float bf2f(ushort u) {
    return __uint_as_float(((uint32_t)u) << 16);
}

// clamp to [0,4] in one VOP3 (median of {m, 0, 4}); rounding-neutral.
static __device__ __forceinline__ float clamp04(float m) {
    float r;
    asm("v_med3_f32 %0, %1, 0, 4.0" : "=v"(r) : "v"(m));
    return r;
}

// u8 spikes (0..4) -> 8 bf16 via v_perm byte-LUT (exact). Verified.
static __device__ __forceinline__ short8v unpack8(uint32_t s0, uint32_t s1) {
    uint32_t lo0 = __builtin_amdgcn_perm(0x00000080u, 0x40008000u, s0);
    uint32_t hi0 = __builtin_amdgcn_perm(0x00000040u, 0x40403F00u, s0);
    uint32_t lo1 = __builtin_amdgcn_perm(0x00000080u, 0x40008000u, s1);
    uint32_t hi1 = __builtin_amdgcn_perm(0x00000040u, 0x40403F00u, s1);
    union { uint32_t u[4]; short8v s; } r;
    r.u[0] = __builtin_amdgcn_perm(hi0, lo0, 0x05010400u);
    r.u[1] = __builtin_amdgcn_perm(hi0, lo0, 0x07030602u);
    r.u[2] = __builtin_amdgcn_perm(hi1, lo1, 0x05010400u);
    r.u[3] = __builtin_amdgcn_perm(hi1, lo1, 0x07030602u);
    return r.s;
}

// async 16B global -> LDS (no dest VGPRs; queue depth = vmcnt)
static __device__ __forceinline__ void gload_lds16(const void* gsrc, void* ldst) {
    __builtin_amdgcn_global_load_lds((const __attribute__((address_space(1))) uint32_t*)gsrc,
                                     (__attribute__((address_space(3))) uint32_t*)ldst, 16, 0, 0);
}

// ---------------------------------------------------------------------------
// Kernel 0: weight prep — fold /4, split bf16 hi+lo, PERMUTED for the conv's
// register preload: dst[((wc*8+ks)*64 + lane)*8 + j] =
//   wq(row = wc*16 + (lane&15), k = ks*32 + (lane>>4)*8 + j)
// ---------------------------------------------------------------------------
__global__ __launch_bounds__(256) void wprep_kernel(const float* __restrict__ w,
                                                    ushort* __restrict__ wh,
                                                    ushort* __restrict__ wl) {
    int gid = blockIdx.x * 256 + threadIdx.x;   // 2048 total
    int lane = gid & 63, ks = (gid >> 6) & 7, wc = gid >> 9;
    int row = wc * 16 + (lane & 15);
    int kb = ks * 32 + (lane >> 4) * 8;
    #pragma unroll
    for (int j = 0; j < 8; ++j) {
        float wq = w[row * 256 + kb + j] * 0.25f;
        ushort h = f2bf_rn(wq);
        wh[gid * 8 + j] = h;
        wl[gid * 8 + j] = f2bf_rn(wq - bf2f(h));
    }
}

// ---------------------------------------------------------------------------
// stage one (t, quarter) x tile (64c x 2rows x 32cols = 16KB) into LDS.
// chunk q = c*2+row (128B); per wave 4 x 1KB gload_lds (8 chunks each).
// ---------------------------------------------------------------------------
static __device__ __forceinline__ void stage_tile(const float* __restrict__ x,
                                                  uint8_t* xb, int t, int b,
                                                  int hs, int quarter, int wid, int lane) {
    const size_t tstr = (size_t)Bn * Cn * Hn * Wn;
    #pragma unroll
    for (int i = 0; i < 4; ++i) {
        int grp = i * 4 + wid;              // 0..15, 1KB each
        int q = 8 * grp + (lane >> 3);      // chunk 0..127
        int cch = q >> 1, row = q & 1;
        const float* gsrc = x + (size_t)t * tstr + ((size_t)b * Cn + cch) * (Hn * Wn)
                            + (2 * hs + row) * Wn + quarter * 32 + (lane & 7) * 4;
        gload_lds16(gsrc, xb + (size_t)grp * 1024);
    }
}

// ---------------------------------------------------------------------------
// Fused LIF + 1x1 conv (low res; conv commutes with bilinear upsample).
// Round-12: SINGLE PASS — 1024 blocks (4/CU exactly), each block = half an
// hs row = TWO quarter-jobs = 8 phases p = q*4 + t. LIF state resets at p=4.
// Tight barC+writeout phase retained (round-10/11 lesson: L2 write-merge).
// vmcnt ledger (stores counted, in-order):
//   issue: S0 W(16) S1 | [p0] S2,y0 | [p1] S3,y1 | ... | [p5] S7,y5 | y6 | y7
//   barA waits: p0=20, p1=5, p2..6=6, p7=2.
// ---------------------------------------------------------------------------
__global__ __launch_bounds__(256, 4) void fused_lif_conv(const float* __restrict__ x,
                                                         const ushort* __restrict__ wh,
                                                         const ushort* __restrict__ wl,
                                                         ushort* __restrict__ y) {
    __shared__ __align__(16) uint8_t xbuf[2][16 * 1024];  // 32 KB double-buffer
    __shared__ __align__(16) uint8_t sp_lds[16 * 256];    // 4 KB spikes [px][k]
    __shared__ __align__(8)  uint8_t y_lds[16 * 128];     // 2 KB [px][c] bf16

    const int tid  = threadIdx.x;
    const int pxl  = tid & 15;          // local pixel (LIF role)
    const int cg   = tid >> 4;          // 0..15 -> channels cg*4..cg*4+3
    const int lane = tid & 63;
    const int wid  = tid >> 6;          // 0..3
    const int l15  = lane & 15;
    const int g    = lane >> 4;
    const int wc   = wid;               // c_out tile (16 c)

    const int bid  = blockIdx.x;        // 1024 = 8 b x 64 hs x 2 half
    const int half = bid & 1;
    const int hs   = (bid >> 1) & 63;
    const int b    = bid >> 7;
    const int c0   = cg * 4;
    const int q0   = half * 2;          // first quarter of this block

    // ---- prologue: S0 (q0,t0), weights (16 loads -> 64 VGPR), S1 (q0,t1) ----
    stage_tile(x, xbuf[0], 0, b, hs, q0, wid, lane);         // S0
    __builtin_amdgcn_sched_barrier(0);
    short8v wrh[8], wrl[8];
    {
        const short8v* ph = (const short8v*)wh + (size_t)(wc * 8) * 64 + lane;
        const short8v* pl = (const short8v*)wl + (size_t)(wc * 8) * 64 + lane;
        #pragma unroll
        for (int ks = 0; ks < 8; ++ks) { wrh[ks] = ph[ks * 64]; wrl[ks] = pl[ks * 64]; }
    }
    __builtin_amdgcn_sched_barrier(0);
    stage_tile(x, xbuf[1], 1, b, hs, q0, wid, lane);         // S1

    float mem[4] = {0.f, 0.f, 0.f, 0.f}, spk[4] = {0.f, 0.f, 0.f, 0.f};

    const int spw  = pxl * 256 + ((cg * 16) ^ ((pxl & 15) << 4));  // spike write
    const int bpx  = l15;                                           // MFMA B pixel
    const int cb   = wc * 4 + g;                                    // c_out quad
    const int ywb  = bpx * 128 + ((cb * 8) ^ ((bpx & 7) << 3));     // y_lds write
    const int crow = tid >> 2;          // writeout c row 0..63
    const int pq   = tid & 3;           // writeout px quad 0..3

    #pragma unroll
    for (int p = 0; p < 8; ++p) {
        const int t       = p & 3;
        const int quarter = q0 + (p >> 2);

        // ---- new spatial sites at p==4: reset LIF state ----
        if (p == 4) {
            #pragma unroll
            for (int i = 0; i < 4; ++i) { mem[i] = 0.f; spk[i] = 0.f; }
        }

        // ---- bar A: wait this phase's stage (counted; y-stores included) ----
        if (p == 0)      WAITV(20);
        else if (p == 1) WAITV(5);
        else if (p == 7) WAITV(2);
        else             WAITV(6);
        BAR();
        __builtin_amdgcn_sched_barrier(0);

        // ---- LIF from LDS, sub-step order = r0.x r0.y r1.x r1.y ----
        const uint8_t* xb = xbuf[p & 1];
        uint32_t pk[4];
        #pragma unroll
        for (int ci = 0; ci < 4; ++ci) {
            int qoff = (c0 + ci) * 256 + pxl * 8;
            float2 r0v = *(const float2*)(xb + qoff);
            float2 r1v = *(const float2*)(xb + qoff + 128);
            float m = mem[ci], s = spk[ci], sv;
            uint32_t pkv;
            m = (m - s) * DECAYF + r0v.x;
            sv = rintf(clamp04(m)); s = sv * 0.25f; pkv = (uint32_t)(int)sv;
            m = (m - s) * DECAYF + r0v.y;
            sv = rintf(clamp04(m)); s = sv * 0.25f; pkv |= ((uint32_t)(int)sv) << 8;
            m = (m - s) * DECAYF + r1v.x;
            sv = rintf(clamp04(m)); s = sv * 0.25f; pkv |= ((uint32_t)(int)sv) << 16;
            m = (m - s) * DECAYF + r1v.y;
            sv = rintf(clamp04(m)); s = sv * 0.25f; pkv |= ((uint32_t)(int)sv) << 24;
            mem[ci] = m; spk[ci] = s; pk[ci] = pkv;
        }
        *(uint4*)(sp_lds + spw) = make_uint4(pk[0], pk[1], pk[2], pk[3]);
        WAITL0();
        BAR();      // bar B: spikes visible; xbuf[p&1] fully consumed

        // ---- prefetch phase p+2 into the buffer just freed ----
        if (p < 6) {
            const int pp = p + 2;
            stage_tile(x, xbuf[p & 1], pp & 3, b, hs, q0 + (pp >> 2), wid, lane);
        }

        // ---- MFMA: 16 x 16x16x32 bf16, zero VMEM in this phase ----
        f32x4 acc = {0.f, 0.f, 0.f, 0.f};
        #pragma unroll
        for (int ks = 0; ks < 8; ++ks) {
            int k0 = ks * 32 + g * 8;
            int rb = bpx * 256 + (k0 ^ ((bpx & 15) << 4));
            uint2 sv2 = *(const uint2*)(sp_lds + rb);
            short8v bfv = unpack8(sv2.x, sv2.y);
            acc = __builtin_amdgcn_mfma_f32_16x16x32_bf16(wrh[ks], bfv, acc, 0, 0, 0);
            acc = __builtin_amdgcn_mfma_f32_16x16x32_bf16(wrl[ks], bfv, acc, 0, 0, 0);
        }

        // ---- epilogue: acc -> y_lds (C/D: col=l15=px, row=g*4+r=c) ----
        uint32_t lo = (uint32_t)f2bf_rn(acc[0]) | ((uint32_t)f2bf_rn(acc[1]) << 16);
        uint32_t hi = (uint32_t)f2bf_rn(acc[2]) | ((uint32_t)f2bf_rn(acc[3]) << 16);
        *(uint2*)(y_lds + ywb) = make_uint2(lo, hi);
        WAITL0();
        BAR();      // bar C: y_lds visible

        // ---- tight writeout phase (keeps partner stores adjacent in time
        //      -> L2 merges the 32B partials into full lines) ----
        ushort v[4];
        #pragma unroll
        for (int j = 0; j < 4; ++j) {
            int pxj = pq * 4 + j;
            int addr = pxj * 128 + (((crow >> 2) * 8) ^ ((pxj & 7) << 3)) + (crow & 3) * 2;
            v[j] = *(const ushort*)(y_lds + addr);
        }
        uint2 o = make_uint2((uint32_t)v[0] | ((uint32_t)v[1] << 16),
                             (uint32_t)v[2] | ((uint32_t)v[3] << 16));
        ushort* yg = y + ((size_t)(t * Bn + b) * Cn + crow) * PX
                       + hs * 64 + quarter * 16 + pq * 4;
        *(uint2*)yg = o;
        // next phase's bar A orders y_lds/sp_lds reuse
    }
}

// ---------------------------------------------------------------------------
// Kernel 3 (unchanged, verified): bilinear 2x upsample, ROW-PAIR + contiguous
// NT stores.
// ---------------------------------------------------------------------------
__global__ __launch_bounds__(256) void upsample_kernel(const ushort* __restrict__ y,
                                                       float* __restrict__ out) {
    const int gg   = blockIdx.x * 256 + threadIdx.x;  // 4194304 threads
    const int sl   = gg & 31;                          // col quad within row
    const int pr   = gg >> 5;                          // row-pair index
    const int m    = pr & 63;
    const int c    = (pr >> 6) & 63;
    const int tb   = pr >> 12;
    const int lane = threadIdx.x & 63;

    const ushort* yp = y + ((size_t)tb * Cn + c) * PX;
    const int rm1 = (m == 0) ? 0 : m - 1;
    const int rp1 = (m == 63) ? 63 : m + 1;

    uint32_t ua = *(const uint32_t*)(yp + rm1 * WsC + 2 * sl);
    uint32_t ub = *(const uint32_t*)(yp + m   * WsC + 2 * sl);
    uint32_t uc = *(const uint32_t*)(yp + rp1 * WsC + 2 * sl);

    float a0 = bf2f((ushort)(ua & 0xffff)), a1 = bf2f((ushort)(ua >> 16));
    float b0 = bf2f((ushort)(ub & 0xffff)), b1 = bf2f((ushort)(ub >> 16));
    float g0 = bf2f((ushort)(uc & 0xffff)), g1 = bf2f((ushort)(uc >> 16));

    float e0 = 0.25f * a0 + 0.75f * b0, e1 = 0.25f * a1 + 0.75f * b1;
    float o0 = 0.75f * b0 + 0.25f * g0, o1 = 0.75f * b1 + 0.25f * g1;

    float eprev = __shfl(e1, lane - 1, 64); if (sl == 0)  eprev = e0;
    float enext = __shfl(e0, lane + 1, 64); if (sl == 31) enext = e1;
    float oprev = __shfl(o1, lane - 1, 64); if (sl == 0)  oprev = o0;
    float onext = __shfl(o0, lane + 1, 64); if (sl == 31) onext = o1;

    f32x4 re, ro;
    re.x = 0.25f * eprev + 0.75f * e0;
    re.y = 0.75f * e0    + 0.25f * e1;
    re.z = 0.25f * e0    + 0.75f * e1;
    re.w = 0.75f * e1    + 0.25f * enext;
    ro.x = 0.25f * oprev + 0.75f * o0;
    ro.y = 0.75f * o0    + 0.25f * o1;
    ro.z = 0.25f * o0    + 0.75f * o1;
    ro.w = 0.75f * o1    + 0.25f * onext;

    float* op = out + ((size_t)tb * Cn + c) * (Hn * Wn) + (size_t)(2 * m) * Wn + 4 * sl;
    __builtin_nontemporal_store(re, (f32x4*)op);
    __builtin_nontemporal_store(ro, (f32x4*)(op + Wn));
}

// ---------------------------------------------------------------------------
extern "C" void kernel_launch(void* const* d_in, const int* in_sizes, int n_in,
                              void* d_out, int out_size, void* d_ws, size_t ws_size,
                              hipStream_t stream) {
    const float* x = (const float*)d_in[0];
    const float* w = (const float*)d_in[1];
    float* out = (float*)d_out;

    ushort* y   = (ushort*)d_ws;                                  // 16,777,216 B
    ushort* whi = (ushort*)((uint8_t*)d_ws + (size_t)16777216);   // 32,768 B
    ushort* wlo = (ushort*)((uint8_t*)d_ws + (size_t)16809984);   // 32,768 B

    wprep_kernel<<<8, 256, 0, stream>>>(w, whi, wlo);
    fused_lif_conv<<<1024, 256, 0, stream>>>(x, whi, wlo, y);
    upsample_kernel<<<16384, 256, 0, stream>>>(y, out);
}

// Round 13
// 57.679 us; speedup vs baseline: 1.0445x; 1.0445x over previous
//
#include <hip/hip_runtime.h>
#include <stdint.h>

constexpr int Bn = 8, Cn = 64, Hn = 128, Wn = 128;
constexpr int HsC = 64, WsC = 64;
constexpr int Kn = 256;                 // C * r^2
constexpr int PX = HsC * WsC;           // 4096 pixels per (t,b) plane
constexpr float DECAYF = 0.25f;

typedef __attribute__((ext_vector_type(8))) short short8v;
typedef __attribute__((ext_vector_type(4))) float f32x4;

#define WAITV(N) asm volatile("s_waitcnt vmcnt(" #N ")" ::: "memory")
#define WAITL0() asm volatile("s_waitcnt lgkmcnt(0)" ::: "memory")
#define BAR() __builtin_amdgcn_s_barrier()

static __device__ __forceinline__ ushort f2bf_rn(float f) {
    uint32_t u = __float_as_uint(f);
    uint32_t r = (u + 0x7FFFu + ((u >> 16) & 1u)) >> 16;
    return (ushort)r;
}
static __device__ __forceinline__ float bf2f(ushort u) {
    return __uint_as_float(((uint32_t)u) << 16);
}

// clamp to [0,4] in one VOP3 (median of {m, 0, 4}); rounding-neutral.
static __device__ __forceinline__ float clamp04(float m) {
    float r;
    asm("v_med3_f32 %0, %1, 0, 4.0" : "=v"(r) : "v"(m));
    return r;
}

// async 16B global -> LDS (no dest VGPRs; queue depth = vmcnt)
static __device__ __forceinline__ void gload_lds16(const void* gsrc, void* ldst) {
    __builtin_amdgcn_global_load_lds((const __attribute__((address_space(1))) uint32_t*)gsrc,
                                     (__attribute__((address_space(3))) uint32_t*)ldst, 16, 0, 0);
}

// ---------------------------------------------------------------------------
// Kernel 0: weight prep — fold /4, split bf16 hi+lo, PERMUTED for the conv's
// register preload: dst[((wc*8+ks)*64 + lane)*8 + j] =
//   wq(row = wc*16 + (lane&15), k = ks*32 + (lane>>4)*8 + j)
// (serves as the MFMA B-operand: lane&15 = c_out col, k contiguous per lane)
// ---------------------------------------------------------------------------
__global__ __launch_bounds__(256) void wprep_kernel(const float* __restrict__ w,
                                                    ushort* __restrict__ wh,
                                                    ushort* __restrict__ wl) {
    int gid = blockIdx.x * 256 + threadIdx.x;   // 2048 total
    int lane = gid & 63, ks = (gid >> 6) & 7, wc = gid >> 9;
    int row = wc * 16 + (lane & 15);
    int kb = ks * 32 + (lane >> 4) * 8;
    #pragma unroll
    for (int j = 0; j < 8; ++j) {
        float wq = w[row * 256 + kb + j] * 0.25f;
        ushort h = f2bf_rn(wq);
        wh[gid * 8 + j] = h;
        wl[gid * 8 + j] = f2bf_rn(wq - bf2f(h));
    }
}

// ---------------------------------------------------------------------------
// stage one t's x tile (64c x 2rows x 32cols = 16KB) into LDS buffer.
// chunk q = c*2+row (128B); per wave 4 x 1KB gload_lds (8 chunks each).
// ---------------------------------------------------------------------------
static __device__ __forceinline__ void stage_tile(const float* __restrict__ x,
                                                  uint8_t* xb, int t, int b,
                                                  int hs, int quarter, int wid, int lane) {
    const size_t tstr = (size_t)Bn * Cn * Hn * Wn;
    #pragma unroll
    for (int i = 0; i < 4; ++i) {
        int grp = i * 4 + wid;              // 0..15, 1KB each
        int q = 8 * grp + (lane >> 3);      // chunk 0..127
        int cch = q >> 1, row = q & 1;
        const float* gsrc = x + (size_t)t * tstr + ((size_t)b * Cn + cch) * (Hn * Wn)
                            + (2 * hs + row) * Wn + quarter * 32 + (lane & 7) * 4;
        gload_lds16(gsrc, xb + (size_t)grp * 1024);
    }
}

// ---------------------------------------------------------------------------
// Fused LIF + 1x1 conv (low res; conv commutes with bilinear upsample).
// Round-13: SWAPPED MFMA OPERANDS — D = mfma(spikes_A, weights_B):
//   C/D: row(reg) = px, col(lane&15) = c_out  =>  each lane stores 4 px of
//   one c-row = 8B contiguous global store. y_lds + barC + writeout DELETED.
// Spikes stored in LDS as bf16 (exact; f32-bits>>16, packed via v_perm) =>
//   MFMA phase is plain swizzled ds_read_b128, no unpack.
// 2 barriers/phase. vmcnt ledger identical to verified round-11:
//   prologue S0(4) W(16) S1(4); per t: stage(4) + ystore(1); waits 20/5/6/2.
// LDS: xbuf 32KB + sp 8KB = 40960B -> 4 blocks/CU.
// ---------------------------------------------------------------------------
__global__ __launch_bounds__(256, 4) void fused_lif_conv(const float* __restrict__ x,
                                                         const ushort* __restrict__ wh,
                                                         const ushort* __restrict__ wl,
                                                         ushort* __restrict__ y) {
    __shared__ __align__(16) uint8_t xbuf[2][16 * 1024];  // 32 KB double-buffer
    __shared__ __align__(16) uint8_t sp_lds[16 * 512];    // 8 KB spikes [px][k] bf16

    const int tid  = threadIdx.x;
    const int pxl  = tid & 15;          // local pixel (LIF role)
    const int cg   = tid >> 4;          // 0..15 -> channels cg*4..cg*4+3
    const int lane = tid & 63;
    const int wid  = tid >> 6;          // 0..3
    const int l15  = lane & 15;
    const int g    = lane >> 4;
    const int wc   = wid;               // c_out tile (16 c)

    const int bid     = blockIdx.x;     // 2048 = 8 b x 64 hs x 4 quarter
    const int quarter = bid & 3;
    const int hs      = (bid >> 2) & 63;
    const int b       = bid >> 8;
    const int c0      = cg * 4;

    // ---- prologue: S0, weights (16 coalesced loads -> 64 VGPR), S1 ----
    stage_tile(x, xbuf[0], 0, b, hs, quarter, wid, lane);    // S0 (4 ops/wave)
    __builtin_amdgcn_sched_barrier(0);
    short8v wrh[8], wrl[8];
    {
        const short8v* ph = (const short8v*)wh + (size_t)(wc * 8) * 64 + lane;
        const short8v* pl = (const short8v*)wl + (size_t)(wc * 8) * 64 + lane;
        #pragma unroll
        for (int ks = 0; ks < 8; ++ks) { wrh[ks] = ph[ks * 64]; wrl[ks] = pl[ks * 64]; }
    }
    __builtin_amdgcn_sched_barrier(0);
    stage_tile(x, xbuf[1], 1, b, hs, quarter, wid, lane);    // S1

    float mem[4] = {0.f, 0.f, 0.f, 0.f}, spk[4] = {0.f, 0.f, 0.f, 0.f};

    const int swz   = (pxl & 7) << 4;                      // LDS 16B-granule XOR
    const int spwb  = pxl * 512 + cg * 32;                 // spike write base
    const int rswz  = (l15 & 7) << 4;                      // MFMA-read XOR

    #pragma unroll
    for (int t = 0; t < 4; ++t) {
        // ---- bar A: wait this t's stage group (counted; y-stores included) ----
        // vmem order: S0(4) W(16) S1(4) | S2(4) yst0 | S3(4) yst1 | yst2
        if (t == 0)      WAITV(20);   // retire S0
        else if (t == 1) WAITV(5);    // retire ..S1
        else if (t == 2) WAITV(6);    // retire ..S2
        else             WAITV(2);    // retire ..S3
        BAR();
        __builtin_amdgcn_sched_barrier(0);

        // ---- LIF t from LDS, sub-step order = r0.x r0.y r1.x r1.y ----
        // spikes -> bf16 pairs via v_perm (sv in {0..4} is bf16-exact)
        const uint8_t* xb = xbuf[t & 1];
        uint32_t pk2[8];
        #pragma unroll
        for (int ci = 0; ci < 4; ++ci) {
            int qoff = (c0 + ci) * 256 + pxl * 8;
            float2 r0v = *(const float2*)(xb + qoff);
            float2 r1v = *(const float2*)(xb + qoff + 128);
            float m = mem[ci], s = spk[ci], sv0, sv1, sv2, sv3;
            m = (m - s) * DECAYF + r0v.x; sv0 = rintf(clamp04(m)); s = sv0 * 0.25f;
            m = (m - s) * DECAYF + r0v.y; sv1 = rintf(clamp04(m)); s = sv1 * 0.25f;
            m = (m - s) * DECAYF + r1v.x; sv2 = rintf(clamp04(m)); s = sv2 * 0.25f;
            m = (m - s) * DECAYF + r1v.y; sv3 = rintf(clamp04(m)); s = sv3 * 0.25f;
            mem[ci] = m; spk[ci] = s;
            pk2[ci * 2 + 0] = __builtin_amdgcn_perm(__float_as_uint(sv1),
                                                    __float_as_uint(sv0), 0x07060302u);
            pk2[ci * 2 + 1] = __builtin_amdgcn_perm(__float_as_uint(sv3),
                                                    __float_as_uint(sv2), 0x07060302u);
        }
        *(uint4*)(sp_lds + ((spwb) ^ swz))      = make_uint4(pk2[0], pk2[1], pk2[2], pk2[3]);
        *(uint4*)(sp_lds + ((spwb + 16) ^ swz)) = make_uint4(pk2[4], pk2[5], pk2[6], pk2[7]);
        WAITL0();
        BAR();      // bar B: spikes visible; xbuf[t&1] fully consumed

        // ---- prefetch t+2 into the buffer just freed ----
        if (t < 2) stage_tile(x, xbuf[t & 1], t + 2, b, hs, quarter, wid, lane);

        // ---- MFMA: A = spikes (row=px), B = weights (col=c_out) ----
        f32x4 acc = {0.f, 0.f, 0.f, 0.f};
        #pragma unroll
        for (int ks = 0; ks < 8; ++ks) {
            int ra = (l15 * 512 + ks * 64 + g * 16) ^ rswz;
            short8v bfv = *(const short8v*)(sp_lds + ra);
            acc = __builtin_amdgcn_mfma_f32_16x16x32_bf16(bfv, wrh[ks], acc, 0, 0, 0);
            acc = __builtin_amdgcn_mfma_f32_16x16x32_bf16(bfv, wrl[ks], acc, 0, 0, 0);
        }

        // ---- direct y store: lane holds 4 consecutive px of c-row (8B) ----
        uint32_t lo = (uint32_t)f2bf_rn(acc[0]) | ((uint32_t)f2bf_rn(acc[1]) << 16);
        uint32_t hi = (uint32_t)f2bf_rn(acc[2]) | ((uint32_t)f2bf_rn(acc[3]) << 16);
        int c = wc * 16 + l15;
        ushort* yg = y + ((size_t)(t * Bn + b) * Cn + c) * PX
                       + hs * 64 + quarter * 16 + g * 4;
        *(uint2*)yg = make_uint2(lo, hi);
        // next phase's bar A orders sp_lds reuse
    }
}

// ---------------------------------------------------------------------------
// Kernel 3 (unchanged, verified): bilinear 2x upsample, ROW-PAIR + contiguous
// NT stores.
// ---------------------------------------------------------------------------
__global__ __launch_bounds__(256) void upsample_kernel(const ushort* __restrict__ y,
                                                       float* __restrict__ out) {
    const int gg   = blockIdx.x * 256 + threadIdx.x;  // 4194304 threads
    const int sl   = gg & 31;                          // col quad within row
    const int pr   = gg >> 5;                          // row-pair index
    const int m    = pr & 63;
    const int c    = (pr >> 6) & 63;
    const int tb   = pr >> 12;
    const int lane = threadIdx.x & 63;

    const ushort* yp = y + ((size_t)tb * Cn + c) * PX;
    const int rm1 = (m == 0) ? 0 : m - 1;
    const int rp1 = (m == 63) ? 63 : m + 1;

    uint32_t ua = *(const uint32_t*)(yp + rm1 * WsC + 2 * sl);
    uint32_t ub = *(const uint32_t*)(yp + m   * WsC + 2 * sl);
    uint32_t uc = *(const uint32_t*)(yp + rp1 * WsC + 2 * sl);

    float a0 = bf2f((ushort)(ua & 0xffff)), a1 = bf2f((ushort)(ua >> 16));
    float b0 = bf2f((ushort)(ub & 0xffff)), b1 = bf2f((ushort)(ub >> 16));
    float g0 = bf2f((ushort)(uc & 0xffff)), g1 = bf2f((ushort)(uc >> 16));

    float e0 = 0.25f * a0 + 0.75f * b0, e1 = 0.25f * a1 + 0.75f * b1;
    float o0 = 0.75f * b0 + 0.25f * g0, o1 = 0.75f * b1 + 0.25f * g1;

    float eprev = __shfl(e1, lane - 1, 64); if (sl == 0)  eprev = e0;
    float enext = __shfl(e0, lane + 1, 64); if (sl == 31) enext = e1;
    float oprev = __shfl(o1, lane - 1, 64); if (sl == 0)  oprev = o0;
    float onext = __shfl(o0, lane + 1, 64); if (sl == 31) onext = o1;

    f32x4 re, ro;
    re.x = 0.25f * eprev + 0.75f * e0;
    re.y = 0.75f * e0    + 0.25f * e1;
    re.z = 0.25f * e0    + 0.75f * e1;
    re.w = 0.75f * e1    + 0.25f * enext;
    ro.x = 0.25f * oprev + 0.75f * o0;
    ro.y = 0.75f * o0    + 0.25f * o1;
    ro.z = 0.25f * o0    + 0.75f * o1;
    ro.w = 0.75f * o1    + 0.25f * onext;

    float* op = out + ((size_t)tb * Cn + c) * (Hn * Wn) + (size_t)(2 * m) * Wn + 4 * sl;
    __builtin_nontemporal_store(re, (f32x4*)op);
    __builtin_nontemporal_store(ro, (f32x4*)(op + Wn));
}

// ---------------------------------------------------------------------------
extern "C" void kernel_launch(void* const* d_in, const int* in_sizes, int n_in,
                              void* d_out, int out_size, void* d_ws, size_t ws_size,
                              hipStream_t stream) {
    const float* x = (const float*)d_in[0];
    const float* w = (const float*)d_in[1];
    float* out = (float*)d_out;

    ushort* y   = (ushort*)d_ws;                                  // 16,777,216 B
    ushort* whi = (ushort*)((uint8_t*)d_ws + (size_t)16777216);   // 32,768 B
    ushort* wlo = (ushort*)((uint8_t*)d_ws + (size_t)16809984);   // 32,768 B

    wprep_kernel<<<8, 256, 0, stream>>>(w, whi, wlo);
    fused_lif_conv<<<2048, 256, 0, stream>>>(x, whi, wlo, y);
    upsample_kernel<<<16384, 256, 0, stream>>>(y, out);
}

// Round 14
// 57.055 us; speedup vs baseline: 1.0559x; 1.0109x over previous
//
#include <hip/hip_runtime.h>
#include <stdint.h>

constexpr int Bn = 8, Cn = 64, Hn = 128, Wn = 128;
constexpr int HsC = 64, WsC = 64;
constexpr int Kn = 256;                 // C * r^2
constexpr int PX = HsC * WsC;           // 4096 pixels per (t,b) plane
constexpr float DECAYF = 0.25f;

typedef __attribute__((ext_vector_type(8))) short short8v;
typedef __attribute__((ext_vector_type(4))) float f32x4;

#define WAITV(N) asm volatile("s_waitcnt vmcnt(" #N ")" ::: "memory")
#define WAITL0() asm volatile("s_waitcnt lgkmcnt(0)" ::: "memory")
#define BAR() __builtin_amdgcn_s_barrier()

static __device__ __forceinline__ ushort f2bf_rn(float f) {
    uint32_t u = __float_as_uint(f);
    uint32_t r = (u + 0x7FFFu + ((u >> 16) & 1u)) >> 16;
    return (ushort)r;
}
static __device__ __forceinline__ float bf2f(ushort u) {
    return __uint_as_float(((uint32_t)u) << 16);
}

// clamp to [0,4] in one VOP3 (median of {m, 0, 4}); rounding-neutral.
static __device__ __forceinline__ float clamp04(float m) {
    float r;
    asm("v_med3_f32 %0, %1, 0, 4.0" : "=v"(r) : "v"(m));
    return r;
}

// async 16B global -> LDS (no dest VGPRs; queue depth = vmcnt)
static __device__ __forceinline__ void gload_lds16(const void* gsrc, void* ldst) {
    __builtin_amdgcn_global_load_lds((const __attribute__((address_space(1))) uint32_t*)gsrc,
                                     (__attribute__((address_space(3))) uint32_t*)ldst, 16, 0, 0);
}

// ---------------------------------------------------------------------------
// Kernel 0: weight prep — fold /4, split bf16 hi+lo, PERMUTED for the conv's
// register preload: dst[((wc*8+ks)*64 + lane)*8 + j] =
//   wq(row = wc*16 + (lane&15), k = ks*32 + (lane>>4)*8 + j)
// 64 blocks, one element per thread.
// ---------------------------------------------------------------------------
__global__ __launch_bounds__(256) void wprep_kernel(const float* __restrict__ w,
                                                    ushort* __restrict__ wh,
                                                    ushort* __restrict__ wl) {
    int tid2 = blockIdx.x * 256 + threadIdx.x;  // 16384 total
    int j = tid2 & 7, gid = tid2 >> 3;
    int lane = gid & 63, ks = (gid >> 6) & 7, wc = gid >> 9;
    int row = wc * 16 + (lane & 15);
    int kb = ks * 32 + (lane >> 4) * 8;
    float wq = w[row * 256 + kb + j] * 0.25f;
    ushort h = f2bf_rn(wq);
    wh[tid2] = h;
    wl[tid2] = f2bf_rn(wq - bf2f(h));
}

// ---------------------------------------------------------------------------
// stage one (t, quarter) x tile (64c x 2rows x 32cols = 16KB) into LDS.
// chunk q = c*2+row (128B); per wave 4 x 1KB gload_lds (8 chunks each).
// LDS layout: x(c,row,col) at byte (c*2+row)*128 + col*4.
// ---------------------------------------------------------------------------
static __device__ __forceinline__ void stage_tile(const float* __restrict__ x,
                                                  uint8_t* xb, int t, int b,
                                                  int hs, int quarter, int wid, int lane) {
    const size_t tstr = (size_t)Bn * Cn * Hn * Wn;
    #pragma unroll
    for (int i = 0; i < 4; ++i) {
        int grp = i * 4 + wid;              // 0..15, 1KB each
        int q = 8 * grp + (lane >> 3);      // chunk 0..127
        int cch = q >> 1, row = q & 1;
        const float* gsrc = x + (size_t)t * tstr + ((size_t)b * Cn + cch) * (Hn * Wn)
                            + (2 * hs + row) * Wn + quarter * 32 + (lane & 7) * 4;
        gload_lds16(gsrc, xb + (size_t)grp * 1024);
    }
}

// ---------------------------------------------------------------------------
// Fused LIF + 1x1 conv (low res; conv commutes with bilinear upsample).
// Round-14: SINGLE PASS (1024 blocks = exactly 4/CU) x 8 phases p = q*4+t,
// with BLOCK-LOCAL y chunks: y[tb][hs][quarter][c][px16] — each block writes
// a dense private 2KB chunk per phase (no partial lines, no L2-merge
// dependence; fixes round-12's hidden write amplification).
// MFMA operand-swapped (round-13): D = mfma(spikes_A, weights_B);
// lane's 4 acc = 4 consecutive px of one c-row -> 8B store into the chunk.
// 2 barriers/phase. vmcnt ledger (stage=4, ystore=1 per phase, W=16):
//   issue: S0 W(16) S1 | S2 y0 | S3 y1 | S4 y2 | S5 y3 | S6 y4 | S7 y5 | y6 | y7
//   barA waits: p0=20, p1=5, p2..6=6, p7=2.
// LDS: xbuf 32KB + sp 8KB = 40960B -> 4 blocks/CU.
// ---------------------------------------------------------------------------
__global__ __launch_bounds__(256, 4) void fused_lif_conv(const float* __restrict__ x,
                                                         const ushort* __restrict__ wh,
                                                         const ushort* __restrict__ wl,
                                                         ushort* __restrict__ y) {
    __shared__ __align__(16) uint8_t xbuf[2][16 * 1024];  // 32 KB double-buffer
    __shared__ __align__(16) uint8_t sp_lds[16 * 512];    // 8 KB spikes [px][k] bf16

    const int tid  = threadIdx.x;
    const int pxl  = tid & 15;          // local pixel (LIF role)
    const int cg   = tid >> 4;          // 0..15 -> channels cg*4..cg*4+3
    const int lane = tid & 63;
    const int wid  = tid >> 6;          // 0..3
    const int l15  = lane & 15;
    const int g    = lane >> 4;
    const int wc   = wid;               // c_out tile (16 c)

    const int bid  = blockIdx.x;        // 1024 = 8 b x 64 hs x 2 half
    const int half = bid & 1;
    const int hs   = (bid >> 1) & 63;
    const int b    = bid >> 7;
    const int c0   = cg * 4;
    const int q0   = half * 2;          // first quarter of this block

    // ---- prologue: S0 (q0,t0), weights (16 coalesced loads), S1 (q0,t1) ----
    stage_tile(x, xbuf[0], 0, b, hs, q0, wid, lane);         // S0 (4 ops/wave)
    __builtin_amdgcn_sched_barrier(0);
    short8v wrh[8], wrl[8];
    {
        const short8v* ph = (const short8v*)wh + (size_t)(wc * 8) * 64 + lane;
        const short8v* pl = (const short8v*)wl + (size_t)(wc * 8) * 64 + lane;
        #pragma unroll
        for (int ks = 0; ks < 8; ++ks) { wrh[ks] = ph[ks * 64]; wrl[ks] = pl[ks * 64]; }
    }
    __builtin_amdgcn_sched_barrier(0);
    stage_tile(x, xbuf[1], 1, b, hs, q0, wid, lane);         // S1

    float mem[4] = {0.f, 0.f, 0.f, 0.f}, spk[4] = {0.f, 0.f, 0.f, 0.f};

    const int swz   = (pxl & 7) << 4;                      // LDS 16B-granule XOR
    const int spwb  = pxl * 512 + cg * 32;                 // spike write base
    const int rswz  = (l15 & 7) << 4;                      // MFMA-read XOR
    const int cout  = wc * 16 + l15;                       // this lane's c-row

    #pragma unroll
    for (int p = 0; p < 8; ++p) {
        const int t       = p & 3;
        const int quarter = q0 + (p >> 2);

        // ---- new spatial sites at p==4: reset LIF state ----
        if (p == 4) {
            #pragma unroll
            for (int i = 0; i < 4; ++i) { mem[i] = 0.f; spk[i] = 0.f; }
        }

        // ---- bar A: wait this phase's stage (counted; y-stores included) ----
        if (p == 0)      WAITV(20);
        else if (p == 1) WAITV(5);
        else if (p == 7) WAITV(2);
        else             WAITV(6);
        BAR();
        __builtin_amdgcn_sched_barrier(0);

        // ---- LIF from LDS, sub-step order = r0.x r0.y r1.x r1.y ----
        // spikes -> bf16 pairs via v_perm (sv in {0..4} is bf16-exact)
        const uint8_t* xb = xbuf[p & 1];
        uint32_t pk2[8];
        #pragma unroll
        for (int ci = 0; ci < 4; ++ci) {
            int qoff = (c0 + ci) * 256 + pxl * 8;
            float2 r0v = *(const float2*)(xb + qoff);
            float2 r1v = *(const float2*)(xb + qoff + 128);
            float m = mem[ci], s = spk[ci], sv0, sv1, sv2, sv3;
            m = (m - s) * DECAYF + r0v.x; sv0 = rintf(clamp04(m)); s = sv0 * 0.25f;
            m = (m - s) * DECAYF + r0v.y; sv1 = rintf(clamp04(m)); s = sv1 * 0.25f;
            m = (m - s) * DECAYF + r1v.x; sv2 = rintf(clamp04(m)); s = sv2 * 0.25f;
            m = (m - s) * DECAYF + r1v.y; sv3 = rintf(clamp04(m)); s = sv3 * 0.25f;
            mem[ci] = m; spk[ci] = s;
            pk2[ci * 2 + 0] = __builtin_amdgcn_perm(__float_as_uint(sv1),
                                                    __float_as_uint(sv0), 0x07060302u);
            pk2[ci * 2 + 1] = __builtin_amdgcn_perm(__float_as_uint(sv3),
                                                    __float_as_uint(sv2), 0x07060302u);
        }
        *(uint4*)(sp_lds + ((spwb) ^ swz))      = make_uint4(pk2[0], pk2[1], pk2[2], pk2[3]);
        *(uint4*)(sp_lds + ((spwb + 16) ^ swz)) = make_uint4(pk2[4], pk2[5], pk2[6], pk2[7]);
        WAITL0();
        BAR();      // bar B: spikes visible; xbuf[p&1] fully consumed

        // ---- prefetch phase p+2 into the buffer just freed ----
        if (p < 6) {
            const int pp = p + 2;
            stage_tile(x, xbuf[p & 1], pp & 3, b, hs, q0 + (pp >> 2), wid, lane);
        }

        // ---- MFMA: A = spikes (row=px), B = weights (col=c_out) ----
        f32x4 acc = {0.f, 0.f, 0.f, 0.f};
        #pragma unroll
        for (int ks = 0; ks < 8; ++ks) {
            int ra = (l15 * 512 + ks * 64 + g * 16) ^ rswz;
            short8v bfv = *(const short8v*)(sp_lds + ra);
            acc = __builtin_amdgcn_mfma_f32_16x16x32_bf16(bfv, wrh[ks], acc, 0, 0, 0);
            acc = __builtin_amdgcn_mfma_f32_16x16x32_bf16(bfv, wrl[ks], acc, 0, 0, 0);
        }

        // ---- y store into BLOCK-LOCAL dense chunk:
        //      y[tb][hs][quarter][c][px16]; lane -> c=cout, px=g*4..g*4+3 ----
        uint32_t lo = (uint32_t)f2bf_rn(acc[0]) | ((uint32_t)f2bf_rn(acc[1]) << 16);
        uint32_t hi = (uint32_t)f2bf_rn(acc[2]) | ((uint32_t)f2bf_rn(acc[3]) << 16);
        ushort* yg = y + (((size_t)(t * Bn + b) * 64 + hs) * 4 + quarter) * 1024
                       + cout * 16 + g * 4;
        *(uint2*)yg = make_uint2(lo, hi);
        // next phase's bar A orders sp_lds reuse
    }
}

// ---------------------------------------------------------------------------
// Kernel 3: bilinear 2x upsample, ROW-PAIR + contiguous NT stores.
// Reads y in the chunked layout y[tb][row][quarter][c][px16].
// ---------------------------------------------------------------------------
__global__ __launch_bounds__(256) void upsample_kernel(const ushort* __restrict__ y,
                                                       float* __restrict__ out) {
    const int gg   = blockIdx.x * 256 + threadIdx.x;  // 4194304 threads
    const int sl   = gg & 31;                          // col quad within row
    const int pr   = gg >> 5;                          // row-pair index
    const int m    = pr & 63;
    const int c    = (pr >> 6) & 63;
    const int tb   = pr >> 12;
    const int lane = threadIdx.x & 63;

    const int rm1 = (m == 0) ? 0 : m - 1;
    const int rp1 = (m == 63) ? 63 : m + 1;
    const int qq      = sl >> 3;           // quarter of cols 2sl, 2sl+1
    const int colpair = (2 * sl) & 15;     // px-pair within quarter

    const size_t boff = c * 16 + colpair;
    uint32_t ua = *(const uint32_t*)(y + (((size_t)tb * 64 + rm1) * 4 + qq) * 1024 + boff);
    uint32_t ub = *(const uint32_t*)(y + (((size_t)tb * 64 + m)   * 4 + qq) * 1024 + boff);
    uint32_t uc = *(const uint32_t*)(y + (((size_t)tb * 64 + rp1) * 4 + qq) * 1024 + boff);

    float a0 = bf2f((ushort)(ua & 0xffff)), a1 = bf2f((ushort)(ua >> 16));
    float b0 = bf2f((ushort)(ub & 0xffff)), b1 = bf2f((ushort)(ub >> 16));
    float g0 = bf2f((ushort)(uc & 0xffff)), g1 = bf2f((ushort)(uc >> 16));

    // vertical: even output row 2m = 0.25*[m-1] + 0.75*[m]; odd = 0.75*[m] + 0.25*[m+1]
    float e0 = 0.25f * a0 + 0.75f * b0, e1 = 0.25f * a1 + 0.75f * b1;
    float o0 = 0.75f * b0 + 0.25f * g0, o1 = 0.75f * b1 + 0.25f * g1;

    float eprev = __shfl(e1, lane - 1, 64); if (sl == 0)  eprev = e0;
    float enext = __shfl(e0, lane + 1, 64); if (sl == 31) enext = e1;
    float oprev = __shfl(o1, lane - 1, 64); if (sl == 0)  oprev = o0;
    float onext = __shfl(o0, lane + 1, 64); if (sl == 31) onext = o1;

    f32x4 re, ro;
    re.x = 0.25f * eprev + 0.75f * e0;
    re.y = 0.75f * e0    + 0.25f * e1;
    re.z = 0.25f * e0    + 0.75f * e1;
    re.w = 0.75f * e1    + 0.25f * enext;
    ro.x = 0.25f * oprev + 0.75f * o0;
    ro.y = 0.75f * o0    + 0.25f * o1;
    ro.z = 0.25f * o0    + 0.75f * o1;
    ro.w = 0.75f * o1    + 0.25f * onext;

    float* op = out + ((size_t)tb * Cn + c) * (Hn * Wn) + (size_t)(2 * m) * Wn + 4 * sl;
    __builtin_nontemporal_store(re, (f32x4*)op);
    __builtin_nontemporal_store(ro, (f32x4*)(op + Wn));
}

// ---------------------------------------------------------------------------
extern "C" void kernel_launch(void* const* d_in, const int* in_sizes, int n_in,
                              void* d_out, int out_size, void* d_ws, size_t ws_size,
                              hipStream_t stream) {
    const float* x = (const float*)d_in[0];
    const float* w = (const float*)d_in[1];
    float* out = (float*)d_out;

    ushort* y   = (ushort*)d_ws;                                  // 16,777,216 B
    ushort* whi = (ushort*)((uint8_t*)d_ws + (size_t)16777216);   // 32,768 B
    ushort* wlo = (ushort*)((uint8_t*)d_ws + (size_t)16809984);   // 32,768 B

    wprep_kernel<<<64, 256, 0, stream>>>(w, whi, wlo);
    fused_lif_conv<<<1024, 256, 0, stream>>>(x, whi, wlo, y);
    upsample_kernel<<<16384, 256, 0, stream>>>(y, out);
}